// Round 15
// baseline (191.897 us; speedup 1.0000x reference)
//
#include <hip/hip_runtime.h>
#include <hip/hip_bf16.h>

// B=16384 W=5 L=20 E=50 V=100000 C=128 H=4096 O=50
// wbf  = bf16 fc1 weights in MFMA A-frag layout:                 ws+8M    (2 MB)
// w2bf = bf16 fc2 weights in MFMA B-frag layout:                 ws+10M   (0.5 MB)
// gt4  = conv table fp16 [128][50][4] = {kk0,kk1,kk2,pad}        ws+11M   (50 KB)
// R14 post-mortem: fp16-conv + rcp-tanh won (fused 110.5->88.4, total 171.8).
// Main loop still 5.4k cyc/chunk vs ~2k port-bound; MfmaUtil 20 / VALU 47 /
// nothing saturated = single-barrier-domain lockstep at 1 block/CU (144KB).
// R15: SAME proven body, halved: 512 blocks x 256 thr (4 waves 2x2),
// 32 rows/block, BK=64 (64 chunks). LDS 71680B (Bs 2x32K + hs 4K; prologue
// table 50K + haS 16K) -> 2 blocks/CU = two independent barrier domains;
// block B's waves cover block A's barrier drain (m114). Wave-private
// handoff preserved: wave's 32 fc1 cols == its fc2 k-frag (kf = chg*2+wc).

typedef __attribute__((ext_vector_type(8))) short short8;
typedef __attribute__((ext_vector_type(4))) float float4v;
typedef __attribute__((ext_vector_type(4))) _Float16 half4v;

__device__ inline short bf16b(float f) {
    __hip_bfloat16 h = __float2bfloat16(f);
    return *reinterpret_cast<short*>(&h);
}
__device__ inline uint packbf2(float a, float b) {
    return (uint)(ushort)bf16b(a) | ((uint)(ushort)bf16b(b) << 16);
}
__device__ inline void gload_lds16(const void* g, void* l) {
    __builtin_amdgcn_global_load_lds(
        (const __attribute__((address_space(1))) unsigned int*)g,
        (__attribute__((address_space(3))) unsigned int*)l, 16, 0, 0);
}
__device__ inline _Float16 hmax(_Float16 a, _Float16 b) { return a > b ? a : b; }

// ---------------------------------------------------------------------------
// Merged prep: wbf (blocks 0..4095), w2bf (..5119), gt4 fp16 (..5194)
// (unchanged from R14, passed)
// ---------------------------------------------------------------------------
__global__ __launch_bounds__(256) void prep_kernel(
    const float* __restrict__ fc1_w, const float* __restrict__ fc1_b,
    const float* __restrict__ fc2_w, const float* __restrict__ char_emb,
    const float* __restrict__ conv_w, short* __restrict__ wbf,
    short* __restrict__ w2bf, _Float16* __restrict__ gt4)
{
    const int bid = blockIdx.x;
    if (bid < 4096) {                       // fc1 weights+bias -> frag order
        int idx = bid * 256 + threadIdx.x;  // n*256 + k
        int n = idx >> 8, k = idx & 255;
        float v = (k < 250) ? fc1_w[n * 250 + k] : (k == 250 ? fc1_b[n] : 0.f);
        int CT = n >> 4, mm = n & 15;
        int ks = k >> 5, qq = (k >> 3) & 3, j = k & 7;
        wbf[((CT * 8 + ks) * 64 + qq * 16 + mm) * 8 + j] = bf16b(v);
    } else if (bid < 5120) {                // fc2 weights (pad 64) -> frag order
        int idx = (bid - 4096) * 256 + threadIdx.x;   // o*4096 + k
        int o = idx >> 12, k = idx & 4095;
        float v = (o < 50) ? fc2_w[idx] : 0.f;
        int Ot = o >> 4, mm = o & 15;
        int kst = k >> 5, qq = (k >> 3) & 3, j = k & 7;
        w2bf[((kst * 4 + Ot) * 64 + qq * 16 + mm) * 8 + j] = bf16b(v);
    } else {                                // conv table -> fp16 [c][o][4] 8B slots
        int idx = (bid - 5120) * 256 + threadIdx.x;   // < 19200
        if (idx >= 19200) return;
        int c = idx / 150, rem = idx - c * 150;
        int kk = rem / 50, o = rem - kk * 50;
        const float* ce = char_emb + c * 50;
        const float* w  = conv_w + o * 150 + kk;
        float s = 0.f;
        #pragma unroll 10
        for (int i = 0; i < 50; ++i) s += ce[i] * w[i * 3];
        gt4[(c * 50 + o) * 4 + kk] = (_Float16)s;
        if (kk == 2) gt4[(c * 50 + o) * 4 + 3] = (_Float16)0.f;   // pad
    }
}

// ---------------------------------------------------------------------------
// Fused conv + fc1 + tanh + fc2 + softmax. 512 blocks x 256 thr, 32 rows.
// LDS map (71680 B declared -> 2 blocks/CU):
//   prologue: gt4 table [0,51200) | cpackS [51200,54400) | xsS [54400,55040)
//             haS (32x256 bf16, XOR-swz) [55040,71424)
//   main:     Bs dbuf [2][2048] frags [0,65536) | hsb [65536,69632)
//   epilogue: partf[2][32][64] fp32 [0,16384)
// Overlap safety: B(0) staging writes [0,32768) only (haS >= 55040);
// buf1/hsb regions overlapping haS are first written after the post-av
// barrier (same discipline as R14, which passed).
// Waves 2x2: wr = wv>>1 (row-tile, 16 rows), wc = wv&1 (col half = k-frag).
// ---------------------------------------------------------------------------
__global__ __launch_bounds__(256, 2) void fused_kernel(
    const int* __restrict__ x, const int* __restrict__ wci,
    const float* __restrict__ word_emb, const float* __restrict__ conv_b,
    const _Float16* __restrict__ gt4, const short* __restrict__ wbf,
    const short* __restrict__ w2bf, const float* __restrict__ fc2_b,
    float* __restrict__ out)
{
    __shared__ char smem[71680];
    short8* Bsv   = (short8*)smem;               // main loop: [2][2048] frags
    char*   hsb   = smem + 65536;                // 4 KB (4 frags)
    float*  partf = (float*)smem;                // epilogue alias
    char*   gsb   = smem;                        // prologue: conv table (50 KB)
    uint*   cpackS = (uint*)(smem + 51200);      // 160 x 5
    int*    xsS    = (int*)(smem + 54400);       // 160
    char*   haS    = smem + 55040;               // 32 rows x 512 B, swizzled

    const int tid  = threadIdx.x;
    const int lane = tid & 63;
    const int wv   = tid >> 6;                   // 0..3
    const int wr = wv >> 1, wc = wv & 1;
    const int q = lane >> 4, m = lane & 15;
    const int m0 = blockIdx.x * 32;
    const int q2base = q >> 1, slot = q & 1;

    const short8* wbfv  = (const short8*)wbf;
    const short8* w2bfv = (const short8*)w2bf;

    // ================= PROLOGUE: conv for this block's 160 words ==========
    {   // stage fp16 table (51200 B) as float4
        const float4* g4 = (const float4*)gt4;
        float4* s4 = (float4*)gsb;
        #pragma unroll
        for (int i = 0; i < 13; ++i) {
            int idx = i * 256 + tid;
            if (idx < 3200) s4[idx] = g4[idx];
        }
    }
    if (tid < 160) {                             // char ids + xid
        const int xid = x[m0 * 5 + tid];
        xsS[tid] = xid;
        const int* crow = wci + (size_t)xid * 20;
        int cid[20];
        #pragma unroll
        for (int p = 0; p < 20; ++p) cid[p] = crow[p];
        #pragma unroll
        for (int u = 0; u < 5; ++u)
            cpackS[tid * 5 + u] = (uint)cid[u * 4] | ((uint)cid[u * 4 + 1] << 8)
                                | ((uint)cid[u * 4 + 2] << 16) | ((uint)cid[u * 4 + 3] << 24);
    }
    // K-bias cols 250..255
    if (tid < 192) {
        const int s = tid / 6, j = tid - s * 6;
        const int byteoff = (s * 512 + (250 + j) * 2) ^ ((s & 7) << 4);
        *(short*)(haS + byteoff) = bf16b(j == 0 ? 1.f : 0.f);
    }
    __syncthreads();

    {   // conv: wave wv handles words (g*8+j)*4+wv; lane = out channel.
        // fp16 adds + max (R14-proven), one cvt at the end.
        const int oc = (lane < 50) ? lane : 49;
        const float cbias = conv_b[oc];
        const int oc8 = oc * 8;
        for (int g = 0; g < 5; ++g) {
            float werv[8];                       // 8 gathers in flight
            #pragma unroll
            for (int j = 0; j < 8; ++j) {
                const int w = (g * 8 + j) * 4 + wv;
                werv[j] = word_emb[(size_t)xsS[w] * 50 + oc];
            }
            #pragma unroll
            for (int j = 0; j < 8; ++j) {
                const int w = (g * 8 + j) * 4 + wv;
                uint cw[5];
                #pragma unroll
                for (int u = 0; u < 5; ++u) cw[u] = cpackS[w * 5 + u];
                int cb[20];
                #pragma unroll
                for (int p = 0; p < 20; ++p) {
                    const int c = (int)((cw[p >> 2] >> ((p & 3) * 8)) & 0xFF);
                    cb[p] = c * 400 + oc8;       // byte offset of 8B slot
                }
                half4v r[11];
                #pragma unroll
                for (int l = 0; l < 11; ++l) r[l] = *(const half4v*)(gsb + cb[l]);
                _Float16 mxh = r[0].y + r[1].z;          // (y+x)+z order kept
                #pragma unroll
                for (int l = 1; l < 10; ++l) {
                    _Float16 s = r[l].y + r[l - 1].x + r[l + 1].z;
                    mxh = hmax(mxh, s);
                }
                const half4v r9 = r[9], r10 = r[10];
                half4v qv[9];
                #pragma unroll
                for (int l = 0; l < 9; ++l) qv[l] = *(const half4v*)(gsb + cb[11 + l]);
                mxh = hmax(mxh, (_Float16)(r10.y + r9.x + qv[0].z));     // l=10
                mxh = hmax(mxh, (_Float16)(qv[0].y + r10.x + qv[1].z));  // l=11
                #pragma unroll
                for (int l = 12; l < 19; ++l) {
                    _Float16 s = qv[l - 11].y + qv[l - 12].x + qv[l - 10].z;
                    mxh = hmax(mxh, s);
                }
                mxh = hmax(mxh, (_Float16)(qv[8].y + qv[7].x));          // l=19

                if (lane < 50) {
                    const int s = w / 5, wp = w - s * 5;
                    const int byteoff = (s * 512 + (wp * 50 + oc) * 2) ^ ((s & 7) << 4);
                    *(short*)(haS + byteoff) = bf16b((float)mxh + cbias + werv[j]);
                }
            }
        }
    }
    __syncthreads();                             // conv done; table dead

    // issue B(0) staging now (writes [0,32768) only; haS untouched)
    #pragma unroll
    for (int i = 0; i < 8; ++i)
        gload_lds16(wbfv + i * 256 + tid, Bsv + i * 256 + tid);

    // ---- A-frags from haS (swizzled b128 reads): 8 frags = 32 VGPR ----
    short8 av[8];
    #pragma unroll
    for (int ks = 0; ks < 8; ++ks) {
        const int r = wr * 16 + m;
        const int byteoff = (r * 512 + ks * 64 + q * 16) ^ ((r & 7) << 4);
        av[ks] = *(const short8*)(haS + byteoff);
    }
    #pragma unroll
    for (int ks = 0; ks < 8; ++ks)
        asm volatile("" : "+v"(av[ks]));
    __syncthreads();                             // drains vmcnt: B(0) ready

    // ================= MAIN LOOP (R14 body, BK=64: 64 chunks) =============
    float4v acc2[4] = {};       // fc2 partial: [out-tile], rows = wr, k += wc

    #pragma unroll 4
    for (int chg = 0; chg < 64; ++chg) {
        const int buf = chg & 1;

        short8 b2[4];
        #pragma unroll
        for (int Ot = 0; Ot < 4; ++Ot)
            b2[Ot] = w2bfv[(size_t)((chg * 2 + wc) * 4 + Ot) * 64 + lane];

        // async prefetch (chg=63 overruns 32KB into w2bf: in-bounds, drained,
        // then the region is never read before being irrelevant)
        #pragma unroll
        for (int i = 0; i < 8; ++i)
            gload_lds16(wbfv + (size_t)(chg + 1) * 2048 + i * 256 + tid,
                        Bsv + (buf ^ 1) * 2048 + i * 256 + tid);

        // ---- fc1: rows [wr*16,+16) x cols [chg*64 + wc*32, +32) ----
        float4v acc[2] = {};
        #pragma unroll
        for (int ks = 0; ks < 8; ++ks) {
            short8 bv[2];
            #pragma unroll
            for (int nt = 0; nt < 2; ++nt)
                bv[nt] = Bsv[buf * 2048 + ((wc * 2 + nt) * 8 + ks) * 64 + lane];
            #pragma unroll
            for (int nt = 0; nt < 2; ++nt)
                acc[nt] = __builtin_amdgcn_mfma_f32_16x16x32_bf16(
                    bv[nt], av[ks], acc[nt], 0, 0, 0);
        }

        // ---- tanh (rcp fast path) + pack to own hs frag (wr, kf=wc) ----
        {
            const int frag = wr * 2 + wc;
            #pragma unroll
            for (int nt = 0; nt < 2; ++nt) {
                float tv[4];
                #pragma unroll
                for (int r = 0; r < 4; ++r) {
                    float rc = __builtin_amdgcn_rcpf(
                        __expf(2.f * acc[nt][r]) + 1.f);
                    tv[r] = fmaf(-2.f, rc, 1.f);
                }
                const int q2 = nt * 2 + q2base;
                const uint p0 = packbf2(tv[0], tv[1]);
                const uint p1 = packbf2(tv[2], tv[3]);
                *(uint2*)(hsb + ((frag * 64 + q2 * 16 + m) * 16 + slot * 8))
                    = make_uint2(p0, p1);
            }
        }

        // ---- fc2 partial: read back OWN frag (same-wave order, no bar) ----
        {
            short8 a2 = *(const short8*)(hsb
                + ((wr * 2 + wc) * 64 + lane) * 16);
            #pragma unroll
            for (int Ot = 0; Ot < 4; ++Ot)
                acc2[Ot] = __builtin_amdgcn_mfma_f32_16x16x32_bf16(
                    a2, b2[Ot], acc2[Ot], 0, 0, 0);
        }

        __syncthreads();    // Bs[buf] reads done + prefetch vmcnt drained
    }

    // ================= EPILOGUE: reduce + bias + softmax ==================
    #pragma unroll
    for (int Ot = 0; Ot < 4; ++Ot)
        #pragma unroll
        for (int r = 0; r < 4; ++r)
            partf[wc * 2048 + (wr * 16 + q * 4 + r) * 64 + Ot * 16 + m]
                = acc2[Ot][r];
    __syncthreads();

    #pragma unroll
    for (int t = 0; t < 8; ++t) {
        int idx = t * 256 + tid;           // row*64 + col, 2048 entries
        int col = idx & 63;
        float lg = partf[idx] + partf[2048 + idx];
        partf[idx] = (col < 50) ? lg + fc2_b[col] : -1e30f;
    }
    __syncthreads();

    #pragma unroll
    for (int rr = 0; rr < 8; ++rr) {
        const int row = wv * 8 + rr;       // 0..31
        float v = partf[row * 64 + lane];
        float mx = v;
        #pragma unroll
        for (int off = 32; off > 0; off >>= 1) mx = fmaxf(mx, __shfl_xor(mx, off));
        float e = __expf(v - mx);
        float s = e;
        #pragma unroll
        for (int off = 32; off > 0; off >>= 1) s += __shfl_xor(s, off);
        if (lane < 50)
            out[(size_t)(m0 + row) * 50 + lane] = e / s;
    }
}

// ---------------------------------------------------------------------------
extern "C" void kernel_launch(void* const* d_in, const int* in_sizes, int n_in,
                              void* d_out, int out_size, void* d_ws, size_t ws_size,
                              hipStream_t stream) {
    const int*   x        = (const int*)  d_in[0];
    const int*   wci      = (const int*)  d_in[1];
    const float* word_emb = (const float*)d_in[2];
    const float* char_emb = (const float*)d_in[3];
    const float* conv_w   = (const float*)d_in[4];
    const float* conv_b   = (const float*)d_in[5];
    const float* fc1_w    = (const float*)d_in[6];
    const float* fc1_b    = (const float*)d_in[7];
    const float* fc2_w    = (const float*)d_in[8];
    const float* fc2_b    = (const float*)d_in[9];
    float* out = (float*)d_out;

    char* ws = (char*)d_ws;
    short* wbf  = (short*)(ws + ((size_t)8  << 20));                  // 2 MB
    short* w2bf = (short*)(ws + ((size_t)10 << 20));                  // 0.5 MB
    _Float16* gt4 = (_Float16*)(ws + ((size_t)11 << 20));             // 50 KB

    prep_kernel<<<5195, 256, 0, stream>>>(fc1_w, fc1_b, fc2_w, char_emb,
                                          conv_w, wbf, w2bf, gt4);
    fused_kernel<<<512, 256, 0, stream>>>(x, wci, word_emb, conv_b, gt4,
                                          wbf, w2bf, fc2_b, out);
}

// Round 17
// 171.085 us; speedup vs baseline: 1.1216x; 1.1216x over previous
//
#include <hip/hip_runtime.h>
#include <hip/hip_bf16.h>

// B=16384 W=5 L=20 E=50 V=100000 C=128 H=4096 O=50
// wbf  = bf16 fc1 weights in MFMA A-frag layout:                 ws+8M    (2 MB)
// w2bf = FP16 fc2 weights in MFMA B-frag layout:                 ws+10M   (0.5 MB)
// gt4  = conv table fp16 [128][50][4] = {kk0,kk1,kk2,pad}        ws+11M   (50 KB)
// R16 failed to COMPILE only: cvt_pkrtz returns __fp16x2, not _Float16x2 --
// fixed with __builtin_bit_cast (same register layout, zero codegen delta).
// Design unchanged: R14 body + h handoff switched bf16->fp16: cvt_pkrtz
// packs acc 2-at-a-time, tanh fully packed f16 (pk_mul/add/fma + v_exp_f16
// + v_rcp_f16, ~64 ops vs ~110), result register IS the packed store; fc2 =
// mfma_f32_16x16x32_f16 (same rate, same C/D layout). tanh-in-f16 error
// ~1.5e-3 rel REPLACES bf16-storage rounding 4e-3 -> absmax ~unchanged.
// Saturation clean: exp2->inf -> rcp->0 -> t=1; exp2->0 -> t=-1.

typedef __attribute__((ext_vector_type(8))) short short8;
typedef __attribute__((ext_vector_type(4))) float float4v;
typedef __attribute__((ext_vector_type(4))) _Float16 half4v;
typedef __attribute__((ext_vector_type(2))) _Float16 half2v;
typedef __attribute__((ext_vector_type(8))) _Float16 half8v;

__device__ inline short bf16b(float f) {
    __hip_bfloat16 h = __float2bfloat16(f);
    return *reinterpret_cast<short*>(&h);
}
__device__ inline void gload_lds16(const void* g, void* l) {
    __builtin_amdgcn_global_load_lds(
        (const __attribute__((address_space(1))) unsigned int*)g,
        (__attribute__((address_space(3))) unsigned int*)l, 16, 0, 0);
}
__device__ inline _Float16 hmax(_Float16 a, _Float16 b) { return a > b ? a : b; }
__device__ inline _Float16 h_exp2(_Float16 x) {
    _Float16 r; asm("v_exp_f16 %0, %1" : "=v"(r) : "v"(x)); return r;
}
__device__ inline _Float16 h_rcp(_Float16 x) {
    _Float16 r; asm("v_rcp_f16 %0, %1" : "=v"(r) : "v"(x)); return r;
}
__device__ inline half2v cvt_pk16(float a, float b) {
    return __builtin_bit_cast(half2v, __builtin_amdgcn_cvt_pkrtz(a, b));
}

// ---------------------------------------------------------------------------
// Merged prep: wbf (blocks 0..4095), w2bf fp16 (..5119), gt4 fp16 (..5194)
// ---------------------------------------------------------------------------
__global__ __launch_bounds__(256) void prep_kernel(
    const float* __restrict__ fc1_w, const float* __restrict__ fc1_b,
    const float* __restrict__ fc2_w, const float* __restrict__ char_emb,
    const float* __restrict__ conv_w, short* __restrict__ wbf,
    short* __restrict__ w2bf, _Float16* __restrict__ gt4)
{
    const int bid = blockIdx.x;
    if (bid < 4096) {                       // fc1 weights+bias -> frag order
        int idx = bid * 256 + threadIdx.x;  // n*256 + k
        int n = idx >> 8, k = idx & 255;
        float v = (k < 250) ? fc1_w[n * 250 + k] : (k == 250 ? fc1_b[n] : 0.f);
        int CT = n >> 4, mm = n & 15;
        int ks = k >> 5, qq = (k >> 3) & 3, j = k & 7;
        wbf[((CT * 8 + ks) * 64 + qq * 16 + mm) * 8 + j] = bf16b(v);
    } else if (bid < 5120) {                // fc2 weights (pad 64) -> FP16 frags
        int idx = (bid - 4096) * 256 + threadIdx.x;   // o*4096 + k
        int o = idx >> 12, k = idx & 4095;
        float v = (o < 50) ? fc2_w[idx] : 0.f;
        int Ot = o >> 4, mm = o & 15;
        int kst = k >> 5, qq = (k >> 3) & 3, j = k & 7;
        _Float16 hv = (_Float16)v;
        w2bf[((kst * 4 + Ot) * 64 + qq * 16 + mm) * 8 + j]
            = *reinterpret_cast<short*>(&hv);
    } else {                                // conv table -> fp16 [c][o][4] 8B slots
        int idx = (bid - 5120) * 256 + threadIdx.x;   // < 19200
        if (idx >= 19200) return;
        int c = idx / 150, rem = idx - c * 150;
        int kk = rem / 50, o = rem - kk * 50;
        const float* ce = char_emb + c * 50;
        const float* w  = conv_w + o * 150 + kk;
        float s = 0.f;
        #pragma unroll 10
        for (int i = 0; i < 50; ++i) s += ce[i] * w[i * 3];
        gt4[(c * 50 + o) * 4 + kk] = (_Float16)s;
        if (kk == 2) gt4[(c * 50 + o) * 4 + 3] = (_Float16)0.f;   // pad
    }
}

// ---------------------------------------------------------------------------
// Fused conv + fc1 + tanh + fc2 + softmax. 256 blocks x 512 thr, 64 rows.
// LDS map (147456 B total): (R14 layout, unchanged)
//   prologue: gt4 table [0,51200) | cpackS [51200,57600) | xsS [..58880)
//             haS (64x256 bf16, XOR-swz) [110080,142848)
//   main:     Bs dbuf [0,131072) | hsb [131072,147456)
//   epilogue: partf[4][64][64] fp32 [0,65536)
// Waves 2x4: wr = wv>>2 (row half), wc = wv&3 (col quarter = fc2 k-frag).
// Wave-private hs handoff -> one __syncthreads per chunk (R8-proven).
// ---------------------------------------------------------------------------
__global__ __launch_bounds__(512, 1) void fused_kernel(
    const int* __restrict__ x, const int* __restrict__ wci,
    const float* __restrict__ word_emb, const float* __restrict__ conv_b,
    const _Float16* __restrict__ gt4, const short* __restrict__ wbf,
    const short* __restrict__ w2bf, const float* __restrict__ fc2_b,
    float* __restrict__ out)
{
    __shared__ char smem[147456];
    short8* Bsv   = (short8*)smem;               // main loop: [2][4096] frags
    char*   hsb   = smem + 131072;               // 16 KB
    float*  partf = (float*)smem;                // epilogue alias
    char*   gsb   = smem;                        // prologue: conv table (50 KB)
    uint*   cpackS = (uint*)(smem + 51200);      // 320 x 5
    int*    xsS    = (int*)(smem + 57600);       // 320
    char*   haS    = smem + 110080;              // 64 rows x 512 B, swizzled

    const int tid  = threadIdx.x;
    const int lane = tid & 63;
    const int wv   = tid >> 6;
    const int wr = wv >> 2, wc = wv & 3;
    const int q = lane >> 4, m = lane & 15;
    const int m0 = blockIdx.x * 64;
    const int q2base = q >> 1, slot = q & 1;

    const short8* wbfv  = (const short8*)wbf;
    const half8v* w2bfv = (const half8v*)w2bf;

    // ================= PROLOGUE: conv for this block's 320 words ==========
    {   // stage fp16 table (51200 B) as float4
        const float4* g4 = (const float4*)gt4;
        float4* s4 = (float4*)gsb;
        #pragma unroll
        for (int i = 0; i < 7; ++i) {
            int idx = i * 512 + tid;
            if (idx < 3200) s4[idx] = g4[idx];
        }
    }
    if (tid < 320) {                             // char ids + xid
        const int xid = x[m0 * 5 + tid];
        xsS[tid] = xid;
        const int* crow = wci + (size_t)xid * 20;
        int cid[20];
        #pragma unroll
        for (int p = 0; p < 20; ++p) cid[p] = crow[p];
        #pragma unroll
        for (int u = 0; u < 5; ++u)
            cpackS[tid * 5 + u] = (uint)cid[u * 4] | ((uint)cid[u * 4 + 1] << 8)
                                | ((uint)cid[u * 4 + 2] << 16) | ((uint)cid[u * 4 + 3] << 24);
    }
    // K-bias cols 250..255 (independent of conv; hoisted off critical path)
    if (tid < 384) {
        const int s = tid / 6, j = tid - s * 6;
        const int byteoff = (s * 512 + (250 + j) * 2) ^ ((s & 7) << 4);
        *(short*)(haS + byteoff) = bf16b(j == 0 ? 1.f : 0.f);
    }
    __syncthreads();

    {   // conv: wave wv handles words (g*8+j)*8+wv; lane = out channel.
        // fp16 adds + running max (R14-proven), one cvt at the end.
        const int oc = (lane < 50) ? lane : 49;
        const float cbias = conv_b[oc];
        const int oc8 = oc * 8;
        for (int g = 0; g < 5; ++g) {
            float werv[8];                       // 8 gathers in flight (MLP)
            #pragma unroll
            for (int j = 0; j < 8; ++j) {
                const int w = (g * 8 + j) * 8 + wv;
                werv[j] = word_emb[(size_t)xsS[w] * 50 + oc];
            }
            #pragma unroll
            for (int j = 0; j < 8; ++j) {
                const int w = (g * 8 + j) * 8 + wv;
                uint cw[5];
                #pragma unroll
                for (int u = 0; u < 5; ++u) cw[u] = cpackS[w * 5 + u];
                int cb[20];
                #pragma unroll
                for (int p = 0; p < 20; ++p) {
                    const int c = (int)((cw[p >> 2] >> ((p & 3) * 8)) & 0xFF);
                    cb[p] = c * 400 + oc8;       // byte offset of 8B slot
                }
                half4v r[11];
                #pragma unroll
                for (int l = 0; l < 11; ++l) r[l] = *(const half4v*)(gsb + cb[l]);
                _Float16 mxh = r[0].y + r[1].z;          // (y+x)+z order kept
                #pragma unroll
                for (int l = 1; l < 10; ++l) {
                    _Float16 s = r[l].y + r[l - 1].x + r[l + 1].z;
                    mxh = hmax(mxh, s);
                }
                const half4v r9 = r[9], r10 = r[10];
                half4v qv[9];
                #pragma unroll
                for (int l = 0; l < 9; ++l) qv[l] = *(const half4v*)(gsb + cb[11 + l]);
                mxh = hmax(mxh, (_Float16)(r10.y + r9.x + qv[0].z));     // l=10
                mxh = hmax(mxh, (_Float16)(qv[0].y + r10.x + qv[1].z));  // l=11
                #pragma unroll
                for (int l = 12; l < 19; ++l) {
                    _Float16 s = qv[l - 11].y + qv[l - 12].x + qv[l - 10].z;
                    mxh = hmax(mxh, s);
                }
                mxh = hmax(mxh, (_Float16)(qv[8].y + qv[7].x));          // l=19

                if (lane < 50) {
                    const int s = w / 5, wp = w - s * 5;
                    const int byteoff = (s * 512 + (wp * 50 + oc) * 2) ^ ((s & 7) << 4);
                    *(short*)(haS + byteoff) = bf16b((float)mxh + cbias + werv[j]);
                }
            }
        }
    }
    __syncthreads();                             // conv done; table dead

    // issue B(0) staging now (overlaps av loads; table region is dead)
    #pragma unroll
    for (int i = 0; i < 8; ++i)
        gload_lds16(wbfv + i * 512 + tid, Bsv + i * 512 + tid);

    // ---- A-frags from haS (swizzled b128 reads): 16 frags = 64 VGPR ----
    short8 av[2][8];
    #pragma unroll
    for (int mt = 0; mt < 2; ++mt)
        #pragma unroll
        for (int ks = 0; ks < 8; ++ks) {
            const int r = wr * 32 + mt * 16 + m;
            const int byteoff = (r * 512 + ks * 64 + q * 16) ^ ((r & 7) << 4);
            av[mt][ks] = *(const short8*)(haS + byteoff);
        }
    #pragma unroll
    for (int mt = 0; mt < 2; ++mt)
        #pragma unroll
        for (int ks = 0; ks < 8; ++ks)
            asm volatile("" : "+v"(av[mt][ks]));
    __syncthreads();                             // drains vmcnt: B(0) ready

    // ================= MAIN LOOP (R14 body, full K: 32 chunks) =============
    float4v acc2[2][4] = {};    // fc2 partial: [row-tile mt][out-tile], k = wc
    const half2v one2 = {(_Float16)1.f, (_Float16)1.f};
    const half2v ntwo2 = {(_Float16)-2.f, (_Float16)-2.f};
    const half2v c2 = {(_Float16)2.8853900817779268f,   // 2*log2(e)
                       (_Float16)2.8853900817779268f};

    #pragma unroll 4
    for (int chg = 0; chg < 32; ++chg) {
        const int buf = chg & 1;

        half8v b2[4];
        #pragma unroll
        for (int Ot = 0; Ot < 4; ++Ot)
            b2[Ot] = w2bfv[(size_t)((chg * 4 + wc) * 4 + Ot) * 64 + lane];

        // async prefetch (chg=31 overruns into w2bf: in-bounds, drained,
        // then overwritten by the partf spill before any read)
        #pragma unroll
        for (int i = 0; i < 8; ++i)
            gload_lds16(wbfv + (size_t)(chg + 1) * 4096 + i * 512 + tid,
                        Bsv + (buf ^ 1) * 4096 + i * 512 + tid);

        // ---- fc1: rows [wr*32,+32) x cols [chg*128 + wc*32, +32) ----
        float4v acc[2][2] = {};
        #pragma unroll
        for (int ks = 0; ks < 8; ++ks) {
            short8 bv[2];
            #pragma unroll
            for (int nt = 0; nt < 2; ++nt)
                bv[nt] = Bsv[buf * 4096 + ((wc * 2 + nt) * 8 + ks) * 64 + lane];
            #pragma unroll
            for (int mt = 0; mt < 2; ++mt)
                #pragma unroll
                for (int nt = 0; nt < 2; ++nt)
                    acc[mt][nt] = __builtin_amdgcn_mfma_f32_16x16x32_bf16(
                        bv[nt], av[mt][ks], acc[mt][nt], 0, 0, 0);
        }

        // ---- tanh fully in packed f16 + store to own hs frags ----
        // t = 1 - 2*rcp(exp2(c*x) + 1); exp2->inf => t=1, exp2->0 => t=-1.
        #pragma unroll
        for (int mt = 0; mt < 2; ++mt) {
            const int frag = (wr * 2 + mt) * 4 + wc;
            #pragma unroll
            for (int nt = 0; nt < 2; ++nt) {
                half2v hp[2];
                #pragma unroll
                for (int pr = 0; pr < 2; ++pr) {
                    half2v xp = cvt_pk16(acc[mt][nt][pr * 2],
                                         acc[mt][nt][pr * 2 + 1]);
                    half2v xc = xp * c2;                 // v_pk_mul_f16
                    half2v e;
                    e.x = h_exp2(xc.x);
                    e.y = h_exp2(xc.y);
                    half2v ep1 = e + one2;               // v_pk_add_f16
                    half2v rc;
                    rc.x = h_rcp(ep1.x);
                    rc.y = h_rcp(ep1.y);
                    hp[pr] = one2 + ntwo2 * rc;          // v_pk_fma_f16
                }
                const int q2 = nt * 2 + q2base;
                const uint p0 = __builtin_bit_cast(uint, hp[0]);
                const uint p1 = __builtin_bit_cast(uint, hp[1]);
                *(uint2*)(hsb + ((frag * 64 + q2 * 16 + m) * 16 + slot * 8))
                    = make_uint2(p0, p1);
            }
        }

        // ---- fc2 partial (f16 MFMA): read back OWN frags, no barrier ----
        {
            half8v a2[2];
            #pragma unroll
            for (int mt = 0; mt < 2; ++mt)
                a2[mt] = *(const half8v*)(hsb
                    + (((wr * 2 + mt) * 4 + wc) * 64 + lane) * 16);
            #pragma unroll
            for (int mt = 0; mt < 2; ++mt)
                #pragma unroll
                for (int Ot = 0; Ot < 4; ++Ot)
                    acc2[mt][Ot] = __builtin_amdgcn_mfma_f32_16x16x32_f16(
                        a2[mt], b2[Ot], acc2[mt][Ot], 0, 0, 0);
        }

        __syncthreads();    // Bs[buf] reads done + prefetch vmcnt drained
    }

    // ================= EPILOGUE: reduce + bias + softmax ==================
    #pragma unroll
    for (int mt = 0; mt < 2; ++mt)
        #pragma unroll
        for (int Ot = 0; Ot < 4; ++Ot)
            #pragma unroll
            for (int r = 0; r < 4; ++r)
                partf[(size_t)wc * 4096
                      + ((wr * 2 + mt) * 16 + q * 4 + r) * 64 + Ot * 16 + m]
                    = acc2[mt][Ot][r];
    __syncthreads();

    #pragma unroll
    for (int t = 0; t < 8; ++t) {
        int idx = t * 512 + tid;           // row*64 + col
        int col = idx & 63;
        float lg = partf[idx] + partf[4096 + idx]
                 + partf[8192 + idx] + partf[12288 + idx];
        partf[idx] = (col < 50) ? lg + fc2_b[col] : -1e30f;
    }
    __syncthreads();

    #pragma unroll
    for (int rr = 0; rr < 8; ++rr) {
        const int row = wv * 8 + rr;
        float v = partf[row * 64 + lane];
        float mx = v;
        #pragma unroll
        for (int off = 32; off > 0; off >>= 1) mx = fmaxf(mx, __shfl_xor(mx, off));
        float e = __expf(v - mx);
        float s = e;
        #pragma unroll
        for (int off = 32; off > 0; off >>= 1) s += __shfl_xor(s, off);
        if (lane < 50)
            out[(size_t)(m0 + row) * 50 + lane] = e / s;
    }
}

// ---------------------------------------------------------------------------
extern "C" void kernel_launch(void* const* d_in, const int* in_sizes, int n_in,
                              void* d_out, int out_size, void* d_ws, size_t ws_size,
                              hipStream_t stream) {
    const int*   x        = (const int*)  d_in[0];
    const int*   wci      = (const int*)  d_in[1];
    const float* word_emb = (const float*)d_in[2];
    const float* char_emb = (const float*)d_in[3];
    const float* conv_w   = (const float*)d_in[4];
    const float* conv_b   = (const float*)d_in[5];
    const float* fc1_w    = (const float*)d_in[6];
    const float* fc1_b    = (const float*)d_in[7];
    const float* fc2_w    = (const float*)d_in[8];
    const float* fc2_b    = (const float*)d_in[9];
    float* out = (float*)d_out;

    char* ws = (char*)d_ws;
    short* wbf  = (short*)(ws + ((size_t)8  << 20));                  // 2 MB
    short* w2bf = (short*)(ws + ((size_t)10 << 20));                  // 0.5 MB
    _Float16* gt4 = (_Float16*)(ws + ((size_t)11 << 20));             // 50 KB

    prep_kernel<<<5195, 256, 0, stream>>>(fc1_w, fc1_b, fc2_w, char_emb,
                                          conv_w, wbf, w2bf, gt4);
    fused_kernel<<<256, 512, 0, stream>>>(x, wci, word_emb, conv_b, gt4,
                                          wbf, w2bf, fc2_b, out);
}